// Round 2
// baseline (242.988 us; speedup 1.0000x reference)
//
#include <hip/hip_runtime.h>

// TeacherEmbeddingTransform: block-diagonal GEMM, fp32.
//   x: (16384, 2304), weight: (25600,1) flat, bias: (576,), out: (16384, 576)
//   Blocks: 16x [16->4], 32x [32->8], 16x [64->16]
// Memory-bound: 151 MB read + 38 MB write => ~30 us floor at 6.3 TB/s.
//
// Scheme: wave = (one matmul-block, 64 rows), lane = row.
//   - Workgroup (256 thr) = 4 consecutive same-size blocks x 64 rows.
//   - x tile staged in LDS via coalesced float4 loads; row stride padded +4
//     floats so per-lane ds_read_b128 (stride % 32 == 4) avoids serializing
//     bank conflicts (>=2-way only, free per m136; LDS BW >> HBM BW anyway).
//   - Weights indexed wave-uniformly (readfirstlane on wave id) -> s_load into
//     SGPRs, FMA reads scalar operand directly; amortized over 64 rows.
//   - Outputs accumulated in VGPRs, stored as float4s (C contiguous cols/lane).

#define BATCH   16384
#define IN_DIM  2304
#define OUT_DIM 576   // 16*4 + 32*8 + 16*16

template <int S, int C>
__global__ __launch_bounds__(256) void block_mm_kernel(
    const float* __restrict__ x, const float* __restrict__ w,
    const float* __restrict__ bias, float* __restrict__ out,
    int t_base, int o_base, int w_base)
{
    constexpr int W    = 4 * S;   // x columns staged per workgroup (4 blocks)
    constexpr int LDSW = W + 4;   // padded row stride: (W+4) % 32 == 4
    __shared__ float xs[64 * LDSW];

    const int tid      = threadIdx.x;
    const int bg       = blockIdx.x;        // group of 4 blocks
    const int row_base = blockIdx.y * 64;

    // ---- stage x tile: 64 rows x W cols, coalesced float4 ----
    const int x_col0 = t_base + bg * W;
    constexpr int VEC_PER_ROW = W / 4;
    constexpr int TOTAL_VEC   = 64 * VEC_PER_ROW;
    #pragma unroll
    for (int i = 0; i < TOTAL_VEC / 256; ++i) {
        const int f  = tid + 256 * i;
        const int r  = f / VEC_PER_ROW;
        const int c4 = f % VEC_PER_ROW;
        const float4 v = *reinterpret_cast<const float4*>(
            x + (size_t)(row_base + r) * IN_DIM + x_col0 + c4 * 4);
        *reinterpret_cast<float4*>(&xs[r * LDSW + c4 * 4]) = v;
    }
    __syncthreads();

    // ---- compute: wave `wid` handles block (4*bg + wid) for 64 rows ----
    const int wid  = __builtin_amdgcn_readfirstlane(tid >> 6);  // uniform
    const int lane = tid & 63;                                  // = row in tile
    const int blk  = bg * 4 + wid;
    const float* __restrict__ wp = w + w_base + blk * (S * C);  // uniform ptr
    const int o_off = o_base + blk * C;

    float acc[C];
    #pragma unroll
    for (int c = 0; c < C; ++c) acc[c] = bias[o_off + c];       // uniform load

    const int xbase = lane * LDSW + wid * S;
    #pragma unroll
    for (int k4 = 0; k4 < S / 4; ++k4) {
        const float4 xv = *reinterpret_cast<const float4*>(&xs[xbase + k4 * 4]);
        #pragma unroll
        for (int j = 0; j < 4; ++j) {
            const float xj = j == 0 ? xv.x : j == 1 ? xv.y : j == 2 ? xv.z : xv.w;
            const int k = k4 * 4 + j;
            #pragma unroll
            for (int c = 0; c < C; ++c)
                acc[c] += xj * wp[k * C + c];                   // s_load weight
        }
    }

    // ---- store: C contiguous floats per lane ----
    float* __restrict__ op = out + (size_t)(row_base + lane) * OUT_DIM + o_off;
    #pragma unroll
    for (int c4 = 0; c4 < C / 4; ++c4) {
        const float4 v = make_float4(acc[c4 * 4 + 0], acc[c4 * 4 + 1],
                                     acc[c4 * 4 + 2], acc[c4 * 4 + 3]);
        *reinterpret_cast<float4*>(op + c4 * 4) = v;
    }
}

extern "C" void kernel_launch(void* const* d_in, const int* in_sizes, int n_in,
                              void* d_out, int out_size, void* d_ws, size_t ws_size,
                              hipStream_t stream) {
    const float* x    = (const float*)d_in[0];
    const float* w    = (const float*)d_in[1];
    const float* bias = (const float*)d_in[2];
    float* out        = (float*)d_out;

    const int row_tiles = BATCH / 64;  // 256

    // group 1: 16 blocks of (16 -> 4): t_base 0,    o_base 0,   w_base 0
    block_mm_kernel<16, 4><<<dim3(4, row_tiles), 256, 0, stream>>>(
        x, w, bias, out, 0, 0, 0);
    // group 2: 32 blocks of (32 -> 8): t_base 256,  o_base 64,  w_base 1024
    block_mm_kernel<32, 8><<<dim3(8, row_tiles), 256, 0, stream>>>(
        x, w, bias, out, 256, 64, 1024);
    // group 3: 16 blocks of (64 -> 16): t_base 1280, o_base 320, w_base 9216
    block_mm_kernel<64, 16><<<dim3(4, row_tiles), 256, 0, stream>>>(
        x, w, bias, out, 1280, 320, 9216);
}

// Round 3
// 228.615 us; speedup vs baseline: 1.0629x; 1.0629x over previous
//
#include <hip/hip_runtime.h>

// TeacherEmbeddingTransform: block-diagonal GEMM, fp32.
//   x: (16384, 2304), weight: (25600,1) flat, bias: (576,), out: (16384, 576)
//   Blocks: 16x [16->4], 32x [32->8], 16x [64->16]
// Memory-bound: 151 MB read + 38 MB write => ~30 us floor at 6.3 TB/s.
//
// FUSED UNIFORM SCHEME: the input splits into 36 chunks of 64 cols, and each
// chunk maps to exactly 16 output cols (g1: 4 blocks 16->4, g2: 2 blocks
// 32->8, g3: 1 block 64->16). Per workgroup (256 thr = 4 waves):
//   - densify the chunk's block-diagonal weights into Wd[64][16] in LDS (4 KB)
//   - stage x tile 64 rows x 64 cols in LDS (stride 68 -> b128 reads at the
//     8-cycle bank floor), coalesced float4 global loads
//   - wave w computes out cols 4w..4w+3 for all 64 rows (lane = row);
//     weights via wave-uniform ds_read_b128 broadcast (no s_load chains,
//     no SGPR pressure); 16 v_fmac per 5 LDS b128 reads
//   - float4 store per lane; 4 waves cover 64 contiguous bytes per row
// One dispatch, 9216 wg, 21.5 KB LDS -> 7 wg/CU (28 waves/CU).

#define BATCH   16384
#define IN_DIM  2304
#define OUT_DIM 576
#define CHUNKS  36
#define XS_LDW  68   // 64 + 4 pad; (68*lane)%32 = 4*lane -> b128 hits 8-cyc floor

__global__ __launch_bounds__(256) void fused_block_mm(
    const float* __restrict__ x, const float* __restrict__ w,
    const float* __restrict__ bias, float* __restrict__ out)
{
    __shared__ float xs[64 * XS_LDW];
    __shared__ float wd[64 * 16];

    const int tid = threadIdx.x;
    const int bx  = blockIdx.x;
    const int cj  = bx % CHUNKS;          // chunk id 0..35 (uniform)
    const int rt  = bx / CHUNKS;          // row tile 0..255
    const int row_base = rt * 64;

    // ---- densify this chunk's weights into wd[64][16] (k-major) ----
    if (cj < 4) {                         // group 1: 4 blocks of 16->4
        const int wbase = cj * 256;
        #pragma unroll
        for (int i = 0; i < 4; ++i) {
            const int e = tid + i * 256, k = e >> 4, c = e & 15, b = k >> 4;
            wd[e] = ((c >> 2) == b)
                  ? w[wbase + b * 64 + ((k & 15) << 2) + (c & 3)] : 0.0f;
        }
    } else if (cj < 20) {                 // group 2: 2 blocks of 32->8
        const int wbase = 1024 + (cj - 4) * 512;
        #pragma unroll
        for (int i = 0; i < 4; ++i) {
            const int e = tid + i * 256, k = e >> 4, c = e & 15, b = k >> 5;
            wd[e] = ((c >> 3) == b)
                  ? w[wbase + b * 256 + ((k & 31) << 3) + (c & 7)] : 0.0f;
        }
    } else {                              // group 3: 1 dense 64->16 block
        const int wbase = 9216 + (cj - 20) * 1024;
        #pragma unroll
        for (int i = 0; i < 4; ++i) {
            const int e = tid + i * 256;
            wd[e] = w[wbase + e];
        }
    }

    // ---- stage x tile: 64 rows x 64 cols, coalesced float4 ----
    const float* __restrict__ xsrc = x + (size_t)row_base * IN_DIM + cj * 64;
    #pragma unroll
    for (int i = 0; i < 4; ++i) {
        const int f = tid + i * 256, r = f >> 4, c = (f & 15) << 2;
        const float4 v = *reinterpret_cast<const float4*>(
            xsrc + (size_t)r * IN_DIM + c);
        *reinterpret_cast<float4*>(&xs[r * XS_LDW + c]) = v;
    }
    __syncthreads();

    // ---- compute: wave wv -> out cols cj*16 + 4*wv .. +3, lane = row ----
    const int wv   = __builtin_amdgcn_readfirstlane(tid >> 6);
    const int lane = tid & 63;
    const int ocol = cj * 16 + (wv << 2);

    float4 acc = make_float4(bias[ocol], bias[ocol + 1],
                             bias[ocol + 2], bias[ocol + 3]);

    const int xb = lane * XS_LDW;
    const int wb = wv << 2;
    #pragma unroll
    for (int k4 = 0; k4 < 16; ++k4) {
        const float4 xv = *reinterpret_cast<const float4*>(&xs[xb + (k4 << 2)]);
        const float4 w0 = *reinterpret_cast<const float4*>(&wd[(k4*4+0)*16 + wb]);
        const float4 w1 = *reinterpret_cast<const float4*>(&wd[(k4*4+1)*16 + wb]);
        const float4 w2 = *reinterpret_cast<const float4*>(&wd[(k4*4+2)*16 + wb]);
        const float4 w3 = *reinterpret_cast<const float4*>(&wd[(k4*4+3)*16 + wb]);
        acc.x += xv.x*w0.x + xv.y*w1.x + xv.z*w2.x + xv.w*w3.x;
        acc.y += xv.x*w0.y + xv.y*w1.y + xv.z*w2.y + xv.w*w3.y;
        acc.z += xv.x*w0.z + xv.y*w1.z + xv.z*w2.z + xv.w*w3.z;
        acc.w += xv.x*w0.w + xv.y*w1.w + xv.z*w2.w + xv.w*w3.w;
    }

    float* __restrict__ op = out + (size_t)(row_base + lane) * OUT_DIM + ocol;
    *reinterpret_cast<float4*>(op) = acc;
}

extern "C" void kernel_launch(void* const* d_in, const int* in_sizes, int n_in,
                              void* d_out, int out_size, void* d_ws, size_t ws_size,
                              hipStream_t stream) {
    const float* x    = (const float*)d_in[0];
    const float* w    = (const float*)d_in[1];
    const float* bias = (const float*)d_in[2];
    float* out        = (float*)d_out;

    const int row_tiles = BATCH / 64;               // 256
    fused_block_mm<<<dim3(CHUNKS * row_tiles), 256, 0, stream>>>(
        x, w, bias, out);
}